// Round 9
// baseline (216.661 us; speedup 1.0000x reference)
//
#include <hip/hip_runtime.h>

#define BATCH 2
#define NVIEW 4
#define NJOINT 24
#define JG 12                      // joints per block (J split in 2)
#define HM 96
#define VOLD 48
#define NVOX (VOLD*VOLD*VOLD)      // 110592
#define IMG (HM*HM)                // 9216
#define CHUNKS 432                 // brick-groups per (b,jg): 1728 bricks / 4 waves
#define TOTAL_BLOCKS (BATCH*2*CHUNKS)   // 1728
#define CNT_OFF 192                // ws word 192 = ticket counter (acc = words 0..191)
#define HMT_OFF 256                // ws float offset of transposed heatmaps
#define RED_STRIDE 260             // LDS reduce row stride

// hm (B,V,J,H,W) -> hmT (B,V,H,W,J); block 0 also zero-inits acc + ticket counter
__global__ __launch_bounds__(256) void transpose_kernel(
    const float* __restrict__ hm, float* __restrict__ hmT,
    float* __restrict__ acc, unsigned* __restrict__ counter)
{
    if (blockIdx.x == 0) {
        if (threadIdx.x < 192) acc[threadIdx.x] = 0.f;
        if (threadIdx.x == 192) *counter = 0u;
    }
    const int o  = blockIdx.x * 256 + threadIdx.x;   // 1,769,472 = 6912*256 exact
    const int j  = o % NJOINT;
    const int r  = o / NJOINT;
    const int xy = r % IMG;
    const int bv = r / IMG;
    hmT[o] = hm[(bv * NJOINT + j) * IMG + xy];       // ~24 lines/wave gather read, coalesced write
}

// block = 4 waves; wave = one 4x4x4 voxel brick; 12 joints per block.
// acc[bj][4] = {sum_w, sum_wx, sum_wy, sum_wz}; last block writes out.
__global__ __launch_bounds__(256, 8) void vol_main_kernel(
    const float* __restrict__ hmT,  // (B,V,H,W,J)
    const float* __restrict__ pm,   // (B,V,3,4)
    const float* __restrict__ cv,   // (B,48,48,48,3)
    float* __restrict__ acc,
    unsigned* __restrict__ counter,
    float* __restrict__ out)
{
    __shared__ float Xt[VOLD], Yt[VOLD], Zt[VOLD];
    __shared__ float red[JG * RED_STRIDE];           // 12.5 KB
    __shared__ float red2[48];
    __shared__ int lastFlag;

    const int tid = threadIdx.x;

    // T1 XCD-chunked swizzle (1728 % 8 == 0): consecutive chunks -> same XCD L2
    const int logical = (blockIdx.x & 7) * (TOTAL_BLOCKS / 8) + (blockIdx.x >> 3);
    const int b   = logical / (2 * CHUNKS);
    const int rem = logical - b * (2 * CHUNKS);
    const int jg  = rem / CHUNKS;
    const int c   = rem - jg * CHUNKS;

    // wave -> brick, lane -> voxel within brick
    const int w    = tid >> 6;
    const int ln   = tid & 63;
    const int beta = c * 4 + w;                      // brick id in [0,1728)
    const int bx   = beta / 144;
    const int r2   = beta - bx * 144;
    const int by   = r2 / 12;
    const int bz   = r2 - by * 12;
    const int x = bx * 4 + (ln >> 4);
    const int y = by * 4 + ((ln >> 2) & 3);
    const int z = bz * 4 + (ln & 3);

    const float* cvb = cv + (size_t)b * NVOX * 3;
    if (tid < VOLD) {   // separable grid: X dep only on x, Y on y, Z on z
        Xt[tid] = cvb[(size_t)tid * (VOLD * VOLD * 3)];
        Yt[tid] = cvb[(size_t)tid * (VOLD * 3) + 1];
        Zt[tid] = cvb[(size_t)tid * 3 + 2];
    }

    float Mv[NVIEW][12];   // uniform per block
#pragma unroll
    for (int v = 0; v < NVIEW; ++v)
#pragma unroll
        for (int k = 0; k < 12; ++k) Mv[v][k] = pm[(b * NVIEW + v) * 12 + k];

    __syncthreads();

    const float X = Xt[x], Y = Yt[y], Z = Zt[z];

    float vol[JG];
#pragma unroll
    for (int q = 0; q < JG; ++q) vol[q] = 0.f;

#pragma unroll
    for (int v = 0; v < NVIEW; ++v) {
        const float* mv = Mv[v];
        const float pz  = fmaf(mv[8], X, fmaf(mv[9], Y, fmaf(mv[10], Z, mv[11])));
        const float pxn = fmaf(mv[0], X, fmaf(mv[1], Y, fmaf(mv[2],  Z, mv[3])));
        const float pyn = fmaf(mv[4], X, fmaf(mv[5], Y, fmaf(mv[6],  Z, mv[7])));

        const float pzc = pz > 0.f ? pz : 1.0f;
        const float inv = __builtin_amdgcn_rcpf(pzc) * (95.0f / 96.0f);
        const float ix  = pxn * inv;
        const float iy  = pyn * inv;

        const float x0f = floorf(ix), y0f = floorf(iy);
        const float wx1 = ix - x0f,  wy1 = iy - y0f;
        const int x0 = (int)x0f, y0 = (int)y0f;
        const int x1 = x0 + 1,   y1 = y0 + 1;

        const bool vz = pz > 0.f;   // reference zeroes samples with z<=0
        const float wx0m = ((unsigned)x0 < (unsigned)HM) ? (1.f - wx1) : 0.f;
        const float wx1m = ((unsigned)x1 < (unsigned)HM) ? wx1 : 0.f;
        const float wy0m = (((unsigned)y0 < (unsigned)HM) && vz) ? (1.f - wy1) : 0.f;
        const float wy1m = (((unsigned)y1 < (unsigned)HM) && vz) ? wy1 : 0.f;

        const float w00 = wy0m * wx0m, w01 = wy0m * wx1m;
        const float w10 = wy1m * wx0m, w11 = wy1m * wx1m;

        const int xc0 = min(max(x0, 0), HM - 1);
        const int xc1 = min(max(x1, 0), HM - 1);
        const int yc0 = min(max(y0, 0), HM - 1);
        const int yc1 = min(max(y1, 0), HM - 1);

        const float* base = hmT + (size_t)(b * NVIEW + v) * (IMG * NJOINT) + jg * JG;
        const float4* p00 = (const float4*)(base + (yc0 * HM + xc0) * NJOINT); // 48B-offset, 16B aligned
        const float4* p01 = (const float4*)(base + (yc0 * HM + xc1) * NJOINT);
        const float4* p10 = (const float4*)(base + (yc1 * HM + xc0) * NJOINT);
        const float4* p11 = (const float4*)(base + (yc1 * HM + xc1) * NJOINT);

#pragma unroll
        for (int c4 = 0; c4 < JG / 4; ++c4) {
            const float4 f00 = p00[c4];
            const float4 f01 = p01[c4];
            const float4 f10 = p10[c4];
            const float4 f11 = p11[c4];
            vol[c4*4+0] = fmaf(w00, f00.x, fmaf(w01, f01.x, fmaf(w10, f10.x, fmaf(w11, f11.x, vol[c4*4+0]))));
            vol[c4*4+1] = fmaf(w00, f00.y, fmaf(w01, f01.y, fmaf(w10, f10.y, fmaf(w11, f11.y, vol[c4*4+1]))));
            vol[c4*4+2] = fmaf(w00, f00.z, fmaf(w01, f01.z, fmaf(w10, f10.z, fmaf(w11, f11.z, vol[c4*4+2]))));
            vol[c4*4+3] = fmaf(w00, f00.w, fmaf(w01, f01.w, fmaf(w10, f10.w, fmaf(w11, f11.w, vol[c4*4+3]))));
        }
    }

    // vol in [0,4] -> exp safe without max subtraction; softmax ratio identical
#pragma unroll
    for (int q = 0; q < JG; ++q) vol[q] = __expf(vol[q]);

    // block reduction: 4 passes over components {w, w*X, w*Y, w*Z}
#pragma unroll
    for (int p = 0; p < 4; ++p) {
        const float scale = (p == 0) ? 1.0f : (p == 1) ? X : (p == 2) ? Y : Z;
#pragma unroll
        for (int q = 0; q < JG; ++q)
            red[q * RED_STRIDE + tid] = vol[q] * scale;
        __syncthreads();

        if (tid < 48) {
            const int q = tid % JG, seg = tid / JG;
            const float4* row = (const float4*)&red[q * RED_STRIDE + seg * 64];
            float s = 0.f;
#pragma unroll
            for (int i = 0; i < 16; ++i) {
                const float4 f = row[i];
                s += (f.x + f.y) + (f.z + f.w);
            }
            red2[seg * JG + q] = s;
        }
        __syncthreads();

        if (tid < JG) {
            const float s = (red2[tid] + red2[tid + JG]) + (red2[tid + 2*JG] + red2[tid + 3*JG]);
            atomicAdd(&acc[(b * NJOINT + jg * JG + tid) * 4 + p], s);
        }
        __syncthreads();
    }

    // last-block finalize (saves a dispatch + graph gap)
    __threadfence();
    __syncthreads();
    if (tid == 0) {
        const unsigned t = atomicAdd(counter, 1u);
        lastFlag = (t == TOTAL_BLOCKS - 1u);
    }
    __syncthreads();
    if (lastFlag && tid < BATCH * NJOINT * 3) {
        const int bj = tid / 3;
        const int cc = tid - bj * 3;
        const float num = atomicAdd(&acc[bj * 4 + 1 + cc], 0.f);  // coherent read
        const float den = atomicAdd(&acc[bj * 4 + 0], 0.f);
        out[tid] = num / den;
    }
}

extern "C" void kernel_launch(void* const* d_in, const int* in_sizes, int n_in,
                              void* d_out, int out_size, void* d_ws, size_t ws_size,
                              hipStream_t stream)
{
    const float* hm = (const float*)d_in[0];   // (B,V,J,96,96)
    const float* pm = (const float*)d_in[1];   // (B,V,3,4)
    const float* cv = (const float*)d_in[2];   // (B,48,48,48,3)
    float* out = (float*)d_out;                // (B,J,3)
    float* acc = (float*)d_ws;                 // 192 floats
    unsigned* counter = (unsigned*)d_ws + CNT_OFF;
    float* hmT = (float*)d_ws + HMT_OFF;       // 7.08 MB transposed heatmaps

    transpose_kernel<<<(BATCH*NVIEW*NJOINT*IMG)/256, 256, 0, stream>>>(hm, hmT, acc, counter);
    vol_main_kernel<<<TOTAL_BLOCKS, 256, 0, stream>>>(hmT, pm, cv, acc, counter, out);
}